// Round 6
// baseline (1071.297 us; speedup 1.0000x reference)
//
#include <hip/hip_runtime.h>

#define Adim 4096
#define HD 128
#define TSTEPS 30
#define NROWS 24576
#define RBLK 32
#define NBLKS 768           // NROWS / RBLK
#define DT_C 0.2f
#define SQDT_C 0.44721359549995794f
#define LN_EPS 1e-5f

#define PI_OFF   2949120    // 6*4096*30*4
#define MASK_OFF 2973696    // PI_OFF + 24576

typedef unsigned short u16;
typedef __bf16 bf16x8 __attribute__((ext_vector_type(8)));
typedef float f32x4 __attribute__((ext_vector_type(4)));

__device__ __forceinline__ u16 f2bf(float x){
    unsigned u = __builtin_bit_cast(unsigned, x);
    u = (u + 0x7fffu + ((u >> 16) & 1u)) >> 16;
    return (u16)u;
}
__device__ __forceinline__ float bf2f(unsigned h){
    unsigned u = (h & 0xffffu) << 16;
    return __builtin_bit_cast(float, u);
}
__device__ __forceinline__ unsigned pack2(float a, float b){
    unsigned r;
    asm("v_cvt_pk_bf16_f32 %0, %1, %2" : "=v"(r) : "v"(a), "v"(b));
    return r;
}
__device__ __forceinline__ float tanh_f(float x){
    return 1.0f - 2.0f / (1.0f + __expf(2.0f * x));
}
__device__ __forceinline__ float sigm_f(float x){
    return 1.0f / (1.0f + __expf(-x));
}
#define SWZ(r,k) ((k) ^ (((r)&7)<<3))
#define MFMA(A,B,C) __builtin_amdgcn_mfma_f32_16x16x32_bf16(A, B, C, 0, 0, 0)

// ---- load this wave's weight a-frags (16 output channels) from L2-hot image ----
__device__ __forceinline__ void loadW(const u16* __restrict__ img, int lane, int wid,
                                      bf16x8 W[4]) {
    const int c = wid*16 + (lane & 15);
    const int kq = lane >> 4;
#pragma unroll
    for (int kk = 0; kk < 4; ++kk)
        W[kk] = *reinterpret_cast<const bf16x8*>(img + c*HD + SWZ(c, kk*32 + kq*8));
}

// ---- GEMMs (swapped): D[c][r] = sum_k W[c][k] act[r][k]; 32 rows = 2 tiles ----
__device__ __forceinline__ void gemm1(const u16* __restrict__ act, const bf16x8 (&W)[4],
                                      int lane, f32x4 acc[2]) {
    const int rl = lane & 15, kq = lane >> 4;
#pragma unroll
    for (int tr = 0; tr < 2; ++tr) {
        const int r = tr*16 + rl;
        const u16* arow = act + r*HD;
        f32x4 a = {0.f,0.f,0.f,0.f};
#pragma unroll
        for (int kk = 0; kk < 4; ++kk) {
            bf16x8 bf = *reinterpret_cast<const bf16x8*>(arow + SWZ(r, kk*32 + kq*8));
            a = MFMA(W[kk], bf, a);
        }
        acc[tr] = a;
    }
}
__device__ __forceinline__ void gemm2(const u16* __restrict__ act,
                                      const bf16x8 (&Wx)[4], const bf16x8 (&Wy)[4],
                                      int lane, f32x4 accX[2], f32x4 accY[2]) {
    const int rl = lane & 15, kq = lane >> 4;
#pragma unroll
    for (int tr = 0; tr < 2; ++tr) {
        const int r = tr*16 + rl;
        const u16* arow = act + r*HD;
        f32x4 ax = {0.f,0.f,0.f,0.f}, ay = {0.f,0.f,0.f,0.f};
#pragma unroll
        for (int kk = 0; kk < 4; ++kk) {
            bf16x8 bf = *reinterpret_cast<const bf16x8*>(arow + SWZ(r, kk*32 + kq*8));
            ax = MFMA(Wx[kk], bf, ax);
            ay = MFMA(Wy[kk], bf, ay);
        }
        accX[tr] = ax; accY[tr] = ay;
    }
}

// ---- epilogues: lane holds 2 row-tiles, 4 consecutive channels ----
__device__ __forceinline__ void epiT(const f32x4 acc[2], const float b[4],
                                     u16* dst, int lane, int wid) {
    const int c0 = wid*16 + ((lane>>4)<<2);
    const int rl = lane & 15;
#pragma unroll
    for (int tr = 0; tr < 2; ++tr) {
        int r = tr*16 + rl;
        float v0 = tanh_f(acc[tr][0] + b[0]);
        float v1 = tanh_f(acc[tr][1] + b[1]);
        float v2 = tanh_f(acc[tr][2] + b[2]);
        float v3 = tanh_f(acc[tr][3] + b[3]);
        uint2 pk = { pack2(v0, v1), pack2(v2, v3) };
        *reinterpret_cast<uint2*>(dst + r*HD + SWZ(r, c0)) = pk;
    }
}
__device__ __forceinline__ void epiN(const f32x4 acc[2], const float b[4],
                                     u16* dst, int lane, int wid) {
    const int c0 = wid*16 + ((lane>>4)<<2);
    const int rl = lane & 15;
#pragma unroll
    for (int tr = 0; tr < 2; ++tr) {
        int r = tr*16 + rl;
        uint2 pk = { pack2(acc[tr][0]+b[0], acc[tr][1]+b[1]),
                     pack2(acc[tr][2]+b[2], acc[tr][3]+b[3]) };
        *reinterpret_cast<uint2*>(dst + r*HD + SWZ(r, c0)) = pk;
    }
}
__device__ __forceinline__ void epiF(const f32x4 acc[2], const float* __restrict__ bias,
                                     float* dst, int lane, int wid) {
    const int c0 = wid*16 + ((lane>>4)<<2);
    const int rl = lane & 15;
    float4 b4 = *reinterpret_cast<const float4*>(bias + c0);
#pragma unroll
    for (int tr = 0; tr < 2; ++tr) {
        int r = tr*16 + rl;
        float4 v = { acc[tr][0]+b4.x, acc[tr][1]+b4.y, acc[tr][2]+b4.z, acc[tr][3]+b4.w };
        *reinterpret_cast<float4*>(dst + r*HD + c0) = v;
    }
}

// ---- prologue GEMM over Xc (lda=256) ----
__device__ __forceinline__ void gemmX(const u16* __restrict__ Xc, int kBase,
                                      const u16* __restrict__ img,
                                      int lane, int wid, f32x4 acc[2], bool init) {
    bf16x8 W[4]; loadW(img, lane, wid, W);
    const int rl = lane & 15, kq = lane >> 4;
#pragma unroll
    for (int tr = 0; tr < 2; ++tr) {
        const int r = tr*16 + rl;
        const u16* arow = Xc + r*256;
        f32x4 a = init ? f32x4{0.f,0.f,0.f,0.f} : acc[tr];
#pragma unroll
        for (int kk = 0; kk < 4; ++kk) {
            bf16x8 bf = *reinterpret_cast<const bf16x8*>(arow + SWZ(r, kBase + kk*32 + kq*8));
            a = MFMA(W[kk], bf, a);
        }
        acc[tr] = a;
    }
}

// ---- LN + relu + 2-wide head; 8 lanes/row; params float4 swizzled in LDS ----
__device__ __forceinline__ void head_ln(const u16* __restrict__ src,
                                        const float4* __restrict__ pp4,
                                        float b20, float b21, int elu, int off, int idx,
                                        float* __restrict__ outStage)
{
    int row = idx >> 3, sub = idx & 7;
    int c0 = sub * 16;
    uint4 p0 = *reinterpret_cast<const uint4*>(src + row*HD + SWZ(row, c0));
    uint4 p1 = *reinterpret_cast<const uint4*>(src + row*HD + SWZ(row, c0+8));
    float v[16];
    v[0]=bf2f(p0.x); v[1]=bf2f(p0.x>>16); v[2]=bf2f(p0.y); v[3]=bf2f(p0.y>>16);
    v[4]=bf2f(p0.z); v[5]=bf2f(p0.z>>16); v[6]=bf2f(p0.w); v[7]=bf2f(p0.w>>16);
    v[8]=bf2f(p1.x); v[9]=bf2f(p1.x>>16); v[10]=bf2f(p1.y); v[11]=bf2f(p1.y>>16);
    v[12]=bf2f(p1.z); v[13]=bf2f(p1.z>>16); v[14]=bf2f(p1.w); v[15]=bf2f(p1.w>>16);
    float s = 0.f, sq = 0.f;
#pragma unroll
    for (int i = 0; i < 16; ++i){ s += v[i]; sq += v[i]*v[i]; }
    s += __shfl_xor(s,1); sq += __shfl_xor(sq,1);
    s += __shfl_xor(s,2); sq += __shfl_xor(sq,2);
    s += __shfl_xor(s,4); sq += __shfl_xor(sq,4);
    float mu = s * (1.f/128.f);
    float rstd = rsqrtf(sq*(1.f/128.f) - mu*mu + LN_EPS);
    float a0 = 0.f, a1 = 0.f;
#pragma unroll
    for (int i = 0; i < 16; ++i){
        float4 p = pp4[(c0 + i) ^ sub];
        float h = (v[i]-mu)*rstd*p.x + p.y;
        h = fmaxf(h, 0.f);
        a0 += h * p.z; a1 += h * p.w;
    }
    a0 += __shfl_xor(a0,1); a1 += __shfl_xor(a1,1);
    a0 += __shfl_xor(a0,2); a1 += __shfl_xor(a1,2);
    a0 += __shfl_xor(a0,4); a1 += __shfl_xor(a1,4);
    if (sub == 0){
        a0 += b20; a1 += b21;
        if (elu){
            a0 = (a0 > 0.f ? a0 : __expf(a0)-1.f) + 1.001f;
            a1 = (a1 > 0.f ? a1 : __expf(a1)-1.f) + 1.001f;
        }
        outStage[row*4 + off]   = a0;
        outStage[row*4 + off+1] = a1;
    }
}

// ---------- weight image prep: f32 -> bf16, transposed, swizzled ----------
__global__ void prep_w(const float* __restrict__ fw1, const float* __restrict__ fw2,
                       const float* __restrict__ fw3, const float* __restrict__ gw1,
                       const float* __restrict__ gw2, const float* __restrict__ dw1,
                       const float* __restrict__ sw1, const float* __restrict__ aw,
                       const float* __restrict__ pw1, u16* __restrict__ ws)
{
    int img = blockIdx.y;
    int idx = blockIdx.x * 256 + threadIdx.x;   // 0..16383
    int k = idx >> 7, j = idx & 127;
    const float* W = fw1; int sr = k;
    switch (img) {
        case 0: W = fw1; break;  case 1: W = fw2; break;  case 2: W = fw3; break;
        case 3: W = gw1; break;  case 4: W = gw2; break;
        case 5: W = dw1; break;  case 6: W = sw1; break;
        case 7: W = aw;  break;  case 8: W = aw;  sr = k + 128; break;
        case 9: W = pw1; break;  case 10: W = pw1; sr = k + 128; break;
    }
    ws[(size_t)img*16384 + j*128 + SWZ(j, k)] = f2bf(W[(size_t)sr*128 + j]);
}

// ---------- final output reorder: ws [blk][tt][row][4] -> loc_out [gr][tt][4] ----------
__global__ void reorder_out(const float* __restrict__ wsOut, float* __restrict__ outp)
{
    __shared__ float tile[3840];
    int b = blockIdx.x;
    const float* src = wsOut + (size_t)b*3840;
#pragma unroll
    for (int j = 0; j < 15; ++j) {
        int idx = j*256 + threadIdx.x;        // tt*128 + row*4 + c
        int tt = idx >> 7, rc = idx & 127;
        int row = rc >> 2, c = idx & 3;
        tile[row*120 + tt*4 + c] = src[idx];
    }
    __syncthreads();
    float* dst = outp + (size_t)b*3840;
#pragma unroll
    for (int j = 0; j < 15; ++j) {
        int idx = j*256 + threadIdx.x;
        dst[idx] = tile[idx];
    }
}

// ---------- the fused persistent kernel ----------
__global__ __launch_bounds__(512, 4) void sde_fused(
    const float* __restrict__ lE, const float* __restrict__ gE,
    const float* __restrict__ noise,
    const float* __restrict__ aggr_b, const float* __restrict__ aggr_g, const float* __restrict__ aggr_be,
    const float* __restrict__ fw1, const float* __restrict__ fb1,
    const float* __restrict__ fb2, const float* __restrict__ fb3,
    const float* __restrict__ gw1, const float* __restrict__ gb1,
    const float* __restrict__ gb2, const float* __restrict__ gw3, const float* __restrict__ gb3,
    const float* __restrict__ db1, const float* __restrict__ dg, const float* __restrict__ dbe,
    const float* __restrict__ dw2, const float* __restrict__ db2,
    const float* __restrict__ sb1, const float* __restrict__ sg, const float* __restrict__ sbe,
    const float* __restrict__ sw2, const float* __restrict__ sb2,
    const float* __restrict__ pb1, const float* __restrict__ pg, const float* __restrict__ pbe,
    const float* __restrict__ pw2, const float* __restrict__ pb2,
    const unsigned char* __restrict__ pmask,
    const u16* __restrict__ wimg,
    float* __restrict__ wsOut,
    float* __restrict__ outp)
{
    // LDS: Sb@0 Ab@8K Bb@16K Cb@24K Fb@32K Db@40K Eb@48K (8K each, 56K total)
    //      biasT @56K (12 x 128 f32 = 6K) | ppd @62K (2K) | pps @64K (2K) | outStage @66K
    // prologue aliases: Xc (16K) @40K (Db+Eb); preLN (16K f32) @8K (Ab+Bb)
    __shared__ __align__(16) unsigned char SMEM[68096];
    u16*  Sb    = (u16*)SMEM;
    u16*  Ab    = (u16*)(SMEM + 8192);
    u16*  Bb    = (u16*)(SMEM + 16384);
    u16*  Cb    = (u16*)(SMEM + 24576);
    u16*  Fb    = (u16*)(SMEM + 32768);
    u16*  Db    = (u16*)(SMEM + 40960);
    u16*  Eb    = (u16*)(SMEM + 49152);
    float* biasT = (float*)(SMEM + 57344);     // [12][128]
    float4* ppd = (float4*)(SMEM + 63488);
    float4* pps = (float4*)(SMEM + 65536);
    float* outStage = (float*)(SMEM + 67584);  // 128 floats
    u16*  Xc    = (u16*)(SMEM + 40960);
    float* preLN = (float*)(SMEM + 8192);

    const int tid  = threadIdx.x;
    const int lane = tid & 63;
    const int wid  = tid >> 6;
    const int bid  = blockIdx.x;
    const int r0   = bid * RBLK;
    const int c0e  = wid*16 + ((lane>>4)<<2);   // this lane's 4 output channels

    // -------- stage params + Xc --------
    if (tid < 128) {
        int cs = tid ^ ((tid >> 4) & 7);
        ppd[cs] = make_float4(dg[tid], dbe[tid], dw2[2*tid], dw2[2*tid+1]);
        pps[cs] = make_float4(sg[tid], sbe[tid], sw2[2*tid], sw2[2*tid+1]);
        biasT[0*128+tid]  = fb1[tid];
        biasT[1*128+tid]  = fw1[128*HD+tid];
        biasT[2*128+tid]  = fw1[129*HD+tid];
        biasT[3*128+tid]  = gb1[tid];
        biasT[4*128+tid]  = gw1[128*HD+tid];
        biasT[5*128+tid]  = gw1[129*HD+tid];
        biasT[6*128+tid]  = fb2[tid];
        biasT[7*128+tid]  = gb2[tid];
        biasT[8*128+tid]  = fb3[tid];
        biasT[9*128+tid]  = db1[tid];
        biasT[10*128+tid] = sb1[tid];
        biasT[11*128+tid] = gw3[tid];
    }
#pragma unroll
    for (int i = 0; i < 2; ++i) {
        int gidx = i*512 + tid;             // 0..1023
        int r = gidx >> 5;
        int k = (gidx & 31) * 8;
        int gr = r0 + r;
        const float* src = (k < HD) ? (gE + (size_t)gr*HD + k)
                                    : (lE + (size_t)(gr & (Adim-1))*HD + (k - HD));
        float4 v0 = reinterpret_cast<const float4*>(src)[0];
        float4 v1 = reinterpret_cast<const float4*>(src)[1];
        uint4 pk = { pack2(v0.x, v0.y), pack2(v0.z, v0.w),
                     pack2(v1.x, v1.y), pack2(v1.z, v1.w) };
        *reinterpret_cast<uint4*>(Xc + r*256 + SWZ(r, k)) = pk;
    }
    __syncthreads();

    f32x4 acc[2];

    // -------- pi head --------
    gemmX(Xc, 0,   wimg + 10*16384, lane, wid, acc, true);   // ge part
    gemmX(Xc, 128, wimg + 9*16384,  lane, wid, acc, false);  // le part
    epiF(acc, pb1, preLN, lane, wid);
    __syncthreads();
    {
        int row = tid >> 4, sub = tid & 15;
        int c0 = sub * 8;
        const float* yr = preLN + row*HD + c0;
        float v[8]; float s = 0.f, sq = 0.f;
#pragma unroll
        for (int i = 0; i < 8; ++i){ float x = yr[i]; v[i] = x; s += x; sq += x*x; }
        s += __shfl_xor(s,1); sq += __shfl_xor(sq,1);
        s += __shfl_xor(s,2); sq += __shfl_xor(sq,2);
        s += __shfl_xor(s,4); sq += __shfl_xor(sq,4);
        s += __shfl_xor(s,8); sq += __shfl_xor(sq,8);
        float mu = s*(1.f/128.f);
        float rstd = rsqrtf(sq*(1.f/128.f) - mu*mu + LN_EPS);
        float a0 = 0.f;
#pragma unroll
        for (int i = 0; i < 8; ++i){
            int cc = c0 + i;
            float h = (v[i]-mu)*rstd*pg[cc] + pbe[cc];
            a0 += fmaxf(h, 0.f) * pw2[cc];
        }
        a0 += __shfl_xor(a0,1); a0 += __shfl_xor(a0,2);
        a0 += __shfl_xor(a0,4); a0 += __shfl_xor(a0,8);
        if (sub == 0) {
            int gr = r0 + row;
            outp[PI_OFF + (size_t)(gr & (Adim-1))*6 + (gr >> 12)] = a0 + pb2[0];
        }
    }
    if (tid < RBLK) {              // reg_mask (rows with m==0)
        int gr = r0 + tid;
        if (gr < Adim) {
            const unsigned char* pm = pmask + (size_t)gr*50 + 20;
            float* o = outp + MASK_OFF + (size_t)gr*TSTEPS;
#pragma unroll
            for (int i = 0; i < TSTEPS; ++i) o[i] = pm[i] ? 0.f : 1.f;
        }
    }
    __syncthreads();

    // -------- aggr head -> h0 --------
    gemmX(Xc, 0,   wimg + 7*16384, lane, wid, acc, true);
    gemmX(Xc, 128, wimg + 8*16384, lane, wid, acc, false);
    __syncthreads();
    epiF(acc, aggr_b, preLN, lane, wid);
    __syncthreads();

    float y0,y1,y2,y3,y4,y5,y6,y7;      // state in registers
    {
        int row = tid >> 4, sub = tid & 15;
        int c0 = sub * 8;
        const float* yr = preLN + row*HD + c0;
        float v[8]; float s = 0.f, sq = 0.f;
#pragma unroll
        for (int i = 0; i < 8; ++i){ float x = yr[i]; v[i] = x; s += x; sq += x*x; }
        s += __shfl_xor(s,1); sq += __shfl_xor(sq,1);
        s += __shfl_xor(s,2); sq += __shfl_xor(sq,2);
        s += __shfl_xor(s,4); sq += __shfl_xor(sq,4);
        s += __shfl_xor(s,8); sq += __shfl_xor(sq,8);
        float mu = s*(1.f/128.f);
        float rstd = rsqrtf(sq*(1.f/128.f) - mu*mu + LN_EPS);
#pragma unroll
        for (int i = 0; i < 8; ++i){
            int cc = c0 + i;
            float h = (v[i]-mu)*rstd*aggr_g[cc] + aggr_be[cc];
            v[i] = fmaxf(h, 0.f);
        }
        y0=v[0]; y1=v[1]; y2=v[2]; y3=v[3]; y4=v[4]; y5=v[5]; y6=v[6]; y7=v[7];
        uint4 pk = { pack2(v[0],v[1]), pack2(v[2],v[3]),
                     pack2(v[4],v[5]), pack2(v[6],v[7]) };
        *reinterpret_cast<uint4*>(&Sb[row*HD + SWZ(row, c0)]) = pk;
    }

    const float db20 = db2[0], db21 = db2[1];
    const float sb20 = sb2[0], sb21 = sb2[1];
    const float gb3v = gb3[0];

    float4 nz0, nz1;
    __syncthreads();

    // -------- PhA(0): L1f,L1g at t=0 + noise prefetch --------
    {
        float bF[4], bG[4];
        {
            float4 b1 = *reinterpret_cast<const float4*>(biasT + 0*128 + c0e);
            float4 cc = *reinterpret_cast<const float4*>(biasT + 2*128 + c0e);
            float4 b2 = *reinterpret_cast<const float4*>(biasT + 3*128 + c0e);
            float4 c2 = *reinterpret_cast<const float4*>(biasT + 5*128 + c0e);
#pragma unroll
            for (int q = 0; q < 4; ++q) {
                bF[q] = ((const float*)&b1)[q] + ((const float*)&cc)[q];
                bG[q] = ((const float*)&b2)[q] + ((const float*)&c2)[q];
            }
        }
        bf16x8 W1[4], W2[4];
        loadW(wimg + 0*16384, lane, wid, W1);
        loadW(wimg + 3*16384, lane, wid, W2);
        f32x4 aF[2], aG[2];
        gemm2(Sb, W1, W2, lane, aF, aG);
        epiT(aF, bF, Ab, lane, wid);
        epiT(aG, bG, Bb, lane, wid);
        const float* np = noise + ((size_t)r0)*HD + (size_t)tid*8;
        nz0 = reinterpret_cast<const float4*>(np)[0];
        nz1 = reinterpret_cast<const float4*>(np)[1];
    }
    __syncthreads();

    // -------- Euler-Maruyama scan: 4 barriers/step --------
    for (int k = 0; k < TSTEPS; ++k) {
        // PhB: L2f(Ab->Cb), L2g(Bb->Fb) + heads for output k-1
        {
            float bF2[4], bG2[4];
            float4 t6 = *reinterpret_cast<const float4*>(biasT + 6*128 + c0e);
            float4 t7 = *reinterpret_cast<const float4*>(biasT + 7*128 + c0e);
#pragma unroll
            for (int q = 0; q < 4; ++q) { bF2[q]=((const float*)&t6)[q]; bG2[q]=((const float*)&t7)[q]; }
            bf16x8 Wf[4];
            loadW(wimg + 1*16384, lane, wid, Wf);
            f32x4 a1[2];
            gemm1(Ab, Wf, lane, a1);
            epiT(a1, bF2, Cb, lane, wid);
            loadW(wimg + 4*16384, lane, wid, Wf);
            gemm1(Bb, Wf, lane, a1);
            epiT(a1, bG2, Fb, lane, wid);
        }
        if (k) {
            if (tid < 256) head_ln(Db, ppd, db20, db21, 0, 0, tid, outStage);
            else           head_ln(Eb, pps, sb20, sb21, 1, 2, tid-256, outStage);
        }
        __syncthreads();
        // PhC: L3f drift (Cb -> Db) + gw3 GEMV (Fb -> reg)
        {
            float bF3[4];
            float4 t8 = *reinterpret_cast<const float4*>(biasT + 8*128 + c0e);
#pragma unroll
            for (int q = 0; q < 4; ++q) bF3[q]=((const float*)&t8)[q];
            bf16x8 Wf[4];
            loadW(wimg + 2*16384, lane, wid, Wf);
            f32x4 a1[2];
            gemm1(Cb, Wf, lane, a1);
            epiN(a1, bF3, Db, lane, wid);
        }
        float growv;
        {
            int row = tid >> 4, sub = tid & 15;
            float4 g0 = *reinterpret_cast<const float4*>(biasT + 11*128 + sub*8);
            float4 g1 = *reinterpret_cast<const float4*>(biasT + 11*128 + sub*8 + 4);
            uint4 pk = *reinterpret_cast<const uint4*>(Fb + row*HD + SWZ(row, sub*8));
            float s = bf2f(pk.x)*g0.x + bf2f(pk.x>>16)*g0.y
                    + bf2f(pk.y)*g0.z + bf2f(pk.y>>16)*g0.w
                    + bf2f(pk.z)*g1.x + bf2f(pk.z>>16)*g1.y
                    + bf2f(pk.w)*g1.z + bf2f(pk.w>>16)*g1.w;
            s += __shfl_xor(s,1); s += __shfl_xor(s,2);
            s += __shfl_xor(s,4); s += __shfl_xor(s,8);
            growv = sigm_f(s + gb3v);
        }
        __syncthreads();
        // PhD: Euler update (state regs) -> Sb
        {
            int row = tid >> 4, sub = tid & 15;
            int sk = SWZ(row, sub*8);
            uint4 dpk = *reinterpret_cast<const uint4*>(Db + row*HD + sk);
            float g = growv * SQDT_C;
            y0 += bf2f(dpk.x)     * DT_C + g*nz0.x;
            y1 += bf2f(dpk.x>>16) * DT_C + g*nz0.y;
            y2 += bf2f(dpk.y)     * DT_C + g*nz0.z;
            y3 += bf2f(dpk.y>>16) * DT_C + g*nz0.w;
            y4 += bf2f(dpk.z)     * DT_C + g*nz1.x;
            y5 += bf2f(dpk.z>>16) * DT_C + g*nz1.y;
            y6 += bf2f(dpk.w)     * DT_C + g*nz1.z;
            y7 += bf2f(dpk.w>>16) * DT_C + g*nz1.w;
            uint4 s4 = { pack2(y0,y1), pack2(y2,y3), pack2(y4,y5), pack2(y6,y7) };
            *reinterpret_cast<uint4*>(Sb + row*HD + sk) = s4;
        }
        __syncthreads();
        // PhA(k+1): L1f,L1g(t_{k+1}) then D1,S1 on new state; nz prefetch; flush
        if (k < TSTEPS-1) {
            float t = (k+1) * DT_C;
            float st = __sinf(t), ct = __cosf(t);
            float bF[4], bG[4], bD[4], bS[4];
            {
                float4 a0 = *reinterpret_cast<const float4*>(biasT + 0*128 + c0e);
                float4 a1 = *reinterpret_cast<const float4*>(biasT + 1*128 + c0e);
                float4 a2 = *reinterpret_cast<const float4*>(biasT + 2*128 + c0e);
                float4 a3 = *reinterpret_cast<const float4*>(biasT + 3*128 + c0e);
                float4 a4 = *reinterpret_cast<const float4*>(biasT + 4*128 + c0e);
                float4 a5 = *reinterpret_cast<const float4*>(biasT + 5*128 + c0e);
                float4 a9 = *reinterpret_cast<const float4*>(biasT + 9*128 + c0e);
                float4 aa = *reinterpret_cast<const float4*>(biasT + 10*128 + c0e);
#pragma unroll
                for (int q = 0; q < 4; ++q) {
                    bF[q] = ((const float*)&a0)[q] + st*((const float*)&a1)[q] + ct*((const float*)&a2)[q];
                    bG[q] = ((const float*)&a3)[q] + st*((const float*)&a4)[q] + ct*((const float*)&a5)[q];
                    bD[q] = ((const float*)&a9)[q];
                    bS[q] = ((const float*)&aa)[q];
                }
            }
            {
                bf16x8 W1[4], W2[4];
                loadW(wimg + 0*16384, lane, wid, W1);
                loadW(wimg + 3*16384, lane, wid, W2);
                f32x4 aF[2], aG[2];
                gemm2(Sb, W1, W2, lane, aF, aG);
                epiT(aF, bF, Ab, lane, wid);
                epiT(aG, bG, Bb, lane, wid);
            }
            {
                bf16x8 W1[4], W2[4];
                loadW(wimg + 5*16384, lane, wid, W1);
                loadW(wimg + 6*16384, lane, wid, W2);
                f32x4 aD[2], aS2[2];
                gemm2(Sb, W1, W2, lane, aD, aS2);
                epiN(aD, bD, Db, lane, wid);
                epiN(aS2, bS, Eb, lane, wid);
            }
            const float* np = noise + ((size_t)(k+1)*NROWS + r0)*HD + (size_t)tid*8;
            nz0 = reinterpret_cast<const float4*>(np)[0];
            nz1 = reinterpret_cast<const float4*>(np)[1];
            if (k >= 1 && tid < 128)
                wsOut[((size_t)bid*TSTEPS + (k-1))*128 + tid] = outStage[tid];
        } else {
            float bD[4], bS[4];
            float4 a9 = *reinterpret_cast<const float4*>(biasT + 9*128 + c0e);
            float4 aa = *reinterpret_cast<const float4*>(biasT + 10*128 + c0e);
#pragma unroll
            for (int q = 0; q < 4; ++q) { bD[q]=((const float*)&a9)[q]; bS[q]=((const float*)&aa)[q]; }
            bf16x8 W1[4], W2[4];
            loadW(wimg + 5*16384, lane, wid, W1);
            loadW(wimg + 6*16384, lane, wid, W2);
            f32x4 aD[2], aS2[2];
            gemm2(Sb, W1, W2, lane, aD, aS2);
            epiN(aD, bD, Db, lane, wid);
            epiN(aS2, bS, Eb, lane, wid);
            if (tid < 128)
                wsOut[((size_t)bid*TSTEPS + (TSTEPS-2))*128 + tid] = outStage[tid];
        }
        __syncthreads();
    }
    // final heads (output TSTEPS-1)
    if (tid < 256) head_ln(Db, ppd, db20, db21, 0, 0, tid, outStage);
    else           head_ln(Eb, pps, sb20, sb21, 1, 2, tid-256, outStage);
    __syncthreads();
    if (tid < 128)
        wsOut[((size_t)bid*TSTEPS + (TSTEPS-1))*128 + tid] = outStage[tid];
}

extern "C" void kernel_launch(void* const* d_in, const int* in_sizes, int n_in,
                              void* d_out, int out_size, void* d_ws, size_t ws_size,
                              hipStream_t stream) {
    const float* lE      = (const float*)d_in[0];
    const float* gE      = (const float*)d_in[1];
    const float* noise   = (const float*)d_in[2];
    const float* aggr_w  = (const float*)d_in[3];
    const float* aggr_b  = (const float*)d_in[4];
    const float* aggr_g  = (const float*)d_in[5];
    const float* aggr_be = (const float*)d_in[6];
    const float* fw1 = (const float*)d_in[7];
    const float* fb1 = (const float*)d_in[8];
    const float* fw2 = (const float*)d_in[9];
    const float* fb2 = (const float*)d_in[10];
    const float* fw3 = (const float*)d_in[11];
    const float* fb3 = (const float*)d_in[12];
    const float* gw1 = (const float*)d_in[13];
    const float* gb1 = (const float*)d_in[14];
    const float* gw2 = (const float*)d_in[15];
    const float* gb2 = (const float*)d_in[16];
    const float* gw3 = (const float*)d_in[17];
    const float* gb3 = (const float*)d_in[18];
    const float* dw1 = (const float*)d_in[19];
    const float* db1 = (const float*)d_in[20];
    const float* dg  = (const float*)d_in[21];
    const float* dbe = (const float*)d_in[22];
    const float* dw2 = (const float*)d_in[23];
    const float* db2 = (const float*)d_in[24];
    const float* sw1 = (const float*)d_in[25];
    const float* sb1 = (const float*)d_in[26];
    const float* sg  = (const float*)d_in[27];
    const float* sbe = (const float*)d_in[28];
    const float* sw2 = (const float*)d_in[29];
    const float* sb2 = (const float*)d_in[30];
    const float* pw1 = (const float*)d_in[31];
    const float* pb1 = (const float*)d_in[32];
    const float* pg  = (const float*)d_in[33];
    const float* pbe = (const float*)d_in[34];
    const float* pw2 = (const float*)d_in[35];
    const float* pb2 = (const float*)d_in[36];
    const unsigned char* pmask = (const unsigned char*)d_in[37];
    float* outp = (float*)d_out;
    u16* wimg = (u16*)d_ws;                                  // 352 KB
    float* wsOut = (float*)((char*)d_ws + 360448);           // 768*3840 floats = 11.8 MB

    prep_w<<<dim3(64, 11), 256, 0, stream>>>(fw1, fw2, fw3, gw1, gw2, dw1, sw1,
                                             aggr_w, pw1, wimg);
    sde_fused<<<NBLKS, 512, 0, stream>>>(
        lE, gE, noise, aggr_b, aggr_g, aggr_be,
        fw1, fb1, fb2, fb3,
        gw1, gb1, gb2, gw3, gb3,
        db1, dg, dbe, dw2, db2,
        sb1, sg, sbe, sw2, sb2,
        pb1, pg, pbe, pw2, pb2,
        pmask, wimg, wsOut, outp);
    reorder_out<<<NBLKS, 256, 0, stream>>>(wsOut, outp);
}

// Round 7
// 879.899 us; speedup vs baseline: 1.2175x; 1.2175x over previous
//
#include <hip/hip_runtime.h>

#define Adim 4096
#define HD 128
#define TSTEPS 30
#define NROWS 24576
#define RBLK 96
#define NBLKS 256           // 256 blocks x 96 rows = 24576; exactly 1 block/CU
#define DT_C 0.2f
#define SQDT_C 0.44721359549995794f
#define LN_EPS 1e-5f

#define PI_OFF   2949120    // 6*4096*30*4
#define MASK_OFF 2973696    // PI_OFF + 24576

typedef unsigned short u16;
typedef __bf16 bf16x8 __attribute__((ext_vector_type(8)));
typedef float f32x4 __attribute__((ext_vector_type(4)));

__device__ __forceinline__ u16 f2bf(float x){
    unsigned u = __builtin_bit_cast(unsigned, x);
    u = (u + 0x7fffu + ((u >> 16) & 1u)) >> 16;
    return (u16)u;
}
__device__ __forceinline__ float bf2f(unsigned h){
    unsigned u = (h & 0xffffu) << 16;
    return __builtin_bit_cast(float, u);
}
__device__ __forceinline__ unsigned pack2(float a, float b){
    unsigned r;
    asm("v_cvt_pk_bf16_f32 %0, %1, %2" : "=v"(r) : "v"(a), "v"(b));
    return r;
}
__device__ __forceinline__ float tanh_f(float x){
    return 1.0f - 2.0f / (1.0f + __expf(2.0f * x));
}
__device__ __forceinline__ float sigm_f(float x){
    return 1.0f / (1.0f + __expf(-x));
}
#define SWZ(r,k) ((k) ^ (((r)&7)<<3))
#define MFMA(A,B,C) __builtin_amdgcn_mfma_f32_16x16x32_bf16(A, B, C, 0, 0, 0)

// ---- per-wave weight fragments: 16 output channels per wave ----
__device__ __forceinline__ void loadW(const u16* __restrict__ img, int lane, int wid,
                                      bf16x8 W[4]) {
    const int c = wid*16 + (lane & 15);
    const int kq = lane >> 4;
#pragma unroll
    for (int kk = 0; kk < 4; ++kk)
        W[kk] = *reinterpret_cast<const bf16x8*>(img + c*HD + SWZ(c, kk*32 + kq*8));
}

// ---- GEMMs (swapped): D[c][r] = sum_k W[c][k] act[r][k]; 32 rows = 2 tiles ----
__device__ __forceinline__ void gemm1(const u16* __restrict__ act, const bf16x8 (&W)[4],
                                      int lane, f32x4 acc[2]) {
    const int rl = lane & 15, kq = lane >> 4;
#pragma unroll
    for (int tr = 0; tr < 2; ++tr) {
        const int r = tr*16 + rl;
        const u16* arow = act + r*HD;
        f32x4 a = {0.f,0.f,0.f,0.f};
#pragma unroll
        for (int kk = 0; kk < 4; ++kk) {
            bf16x8 bf = *reinterpret_cast<const bf16x8*>(arow + SWZ(r, kk*32 + kq*8));
            a = MFMA(W[kk], bf, a);
        }
        acc[tr] = a;
    }
}
__device__ __forceinline__ void gemm2(const u16* __restrict__ act,
                                      const bf16x8 (&Wx)[4], const bf16x8 (&Wy)[4],
                                      int lane, f32x4 accX[2], f32x4 accY[2]) {
    const int rl = lane & 15, kq = lane >> 4;
#pragma unroll
    for (int tr = 0; tr < 2; ++tr) {
        const int r = tr*16 + rl;
        const u16* arow = act + r*HD;
        f32x4 ax = {0.f,0.f,0.f,0.f}, ay = {0.f,0.f,0.f,0.f};
#pragma unroll
        for (int kk = 0; kk < 4; ++kk) {
            bf16x8 bf = *reinterpret_cast<const bf16x8*>(arow + SWZ(r, kk*32 + kq*8));
            ax = MFMA(Wx[kk], bf, ax);
            ay = MFMA(Wy[kk], bf, ay);
        }
        accX[tr] = ax; accY[tr] = ay;
    }
}
__device__ __forceinline__ void gemm4(const u16* __restrict__ act,
                                      const bf16x8 (&W1)[4], const bf16x8 (&W2)[4],
                                      const bf16x8 (&W3)[4], const bf16x8 (&W4)[4],
                                      int lane, f32x4 a1[2], f32x4 a2[2],
                                      f32x4 a3[2], f32x4 a4[2]) {
    const int rl = lane & 15, kq = lane >> 4;
#pragma unroll
    for (int tr = 0; tr < 2; ++tr) {
        const int r = tr*16 + rl;
        const u16* arow = act + r*HD;
        f32x4 x1={0.f,0.f,0.f,0.f}, x2={0.f,0.f,0.f,0.f};
        f32x4 x3={0.f,0.f,0.f,0.f}, x4={0.f,0.f,0.f,0.f};
#pragma unroll
        for (int kk = 0; kk < 4; ++kk) {
            bf16x8 bf = *reinterpret_cast<const bf16x8*>(arow + SWZ(r, kk*32 + kq*8));
            x1 = MFMA(W1[kk], bf, x1);
            x2 = MFMA(W2[kk], bf, x2);
            x3 = MFMA(W3[kk], bf, x3);
            x4 = MFMA(W4[kk], bf, x4);
        }
        a1[tr]=x1; a2[tr]=x2; a3[tr]=x3; a4[tr]=x4;
    }
}

// ---- epilogues ----
__device__ __forceinline__ void epiT(const f32x4 acc[2], const float b[4],
                                     u16* dst, int lane, int wid) {
    const int c0 = wid*16 + ((lane>>4)<<2);
    const int rl = lane & 15;
#pragma unroll
    for (int tr = 0; tr < 2; ++tr) {
        int r = tr*16 + rl;
        float v0 = tanh_f(acc[tr][0] + b[0]);
        float v1 = tanh_f(acc[tr][1] + b[1]);
        float v2 = tanh_f(acc[tr][2] + b[2]);
        float v3 = tanh_f(acc[tr][3] + b[3]);
        uint2 pk = { pack2(v0, v1), pack2(v2, v3) };
        *reinterpret_cast<uint2*>(dst + r*HD + SWZ(r, c0)) = pk;
    }
}
__device__ __forceinline__ void epiN(const f32x4 acc[2], const float b[4],
                                     u16* dst, int lane, int wid) {
    const int c0 = wid*16 + ((lane>>4)<<2);
    const int rl = lane & 15;
#pragma unroll
    for (int tr = 0; tr < 2; ++tr) {
        int r = tr*16 + rl;
        uint2 pk = { pack2(acc[tr][0]+b[0], acc[tr][1]+b[1]),
                     pack2(acc[tr][2]+b[2], acc[tr][3]+b[3]) };
        *reinterpret_cast<uint2*>(dst + r*HD + SWZ(r, c0)) = pk;
    }
}
__device__ __forceinline__ void epiF(const f32x4 acc[2], const float* __restrict__ bias,
                                     float* dst, int lane, int wid) {
    const int c0 = wid*16 + ((lane>>4)<<2);
    const int rl = lane & 15;
    float4 b4 = *reinterpret_cast<const float4*>(bias + c0);
#pragma unroll
    for (int tr = 0; tr < 2; ++tr) {
        int r = tr*16 + rl;
        float4 v = { acc[tr][0]+b4.x, acc[tr][1]+b4.y, acc[tr][2]+b4.z, acc[tr][3]+b4.w };
        *reinterpret_cast<float4*>(dst + r*HD + c0) = v;
    }
}

// ---- prologue GEMM over Xc (lda=256) ----
__device__ __forceinline__ void gemmX(const u16* __restrict__ Xc, int kBase,
                                      const u16* __restrict__ img,
                                      int lane, int wid, f32x4 acc[2], bool init) {
    bf16x8 W[4]; loadW(img, lane, wid, W);
    const int rl = lane & 15, kq = lane >> 4;
#pragma unroll
    for (int tr = 0; tr < 2; ++tr) {
        const int r = tr*16 + rl;
        const u16* arow = Xc + r*256;
        f32x4 a = init ? f32x4{0.f,0.f,0.f,0.f} : acc[tr];
#pragma unroll
        for (int kk = 0; kk < 4; ++kk) {
            bf16x8 bf = *reinterpret_cast<const bf16x8*>(arow + SWZ(r, kBase + kk*32 + kq*8));
            a = MFMA(W[kk], bf, a);
        }
        acc[tr] = a;
    }
}

// ---- LN + relu + 2-wide head; 8 lanes/row; params float4 swizzled in LDS ----
__device__ __forceinline__ void head_ln(const u16* __restrict__ src,
                                        const float4* __restrict__ pp4,
                                        float b20, float b21, int elu, int off, int idx,
                                        float* __restrict__ outStage)
{
    int row = idx >> 3, sub = idx & 7;
    int c0 = sub * 16;
    uint4 p0 = *reinterpret_cast<const uint4*>(src + row*HD + SWZ(row, c0));
    uint4 p1 = *reinterpret_cast<const uint4*>(src + row*HD + SWZ(row, c0+8));
    float v[16];
    v[0]=bf2f(p0.x); v[1]=bf2f(p0.x>>16); v[2]=bf2f(p0.y); v[3]=bf2f(p0.y>>16);
    v[4]=bf2f(p0.z); v[5]=bf2f(p0.z>>16); v[6]=bf2f(p0.w); v[7]=bf2f(p0.w>>16);
    v[8]=bf2f(p1.x); v[9]=bf2f(p1.x>>16); v[10]=bf2f(p1.y); v[11]=bf2f(p1.y>>16);
    v[12]=bf2f(p1.z); v[13]=bf2f(p1.z>>16); v[14]=bf2f(p1.w); v[15]=bf2f(p1.w>>16);
    float s = 0.f, sq = 0.f;
#pragma unroll
    for (int i = 0; i < 16; ++i){ s += v[i]; sq += v[i]*v[i]; }
    s += __shfl_xor(s,1); sq += __shfl_xor(sq,1);
    s += __shfl_xor(s,2); sq += __shfl_xor(sq,2);
    s += __shfl_xor(s,4); sq += __shfl_xor(sq,4);
    float mu = s * (1.f/128.f);
    float rstd = rsqrtf(sq*(1.f/128.f) - mu*mu + LN_EPS);
    float a0 = 0.f, a1 = 0.f;
#pragma unroll
    for (int i = 0; i < 16; ++i){
        float4 p = pp4[(c0 + i) ^ sub];
        float h = (v[i]-mu)*rstd*p.x + p.y;
        h = fmaxf(h, 0.f);
        a0 += h * p.z; a1 += h * p.w;
    }
    a0 += __shfl_xor(a0,1); a1 += __shfl_xor(a1,1);
    a0 += __shfl_xor(a0,2); a1 += __shfl_xor(a1,2);
    a0 += __shfl_xor(a0,4); a1 += __shfl_xor(a1,4);
    if (sub == 0){
        a0 += b20; a1 += b21;
        if (elu){
            a0 = (a0 > 0.f ? a0 : __expf(a0)-1.f) + 1.001f;
            a1 = (a1 > 0.f ? a1 : __expf(a1)-1.f) + 1.001f;
        }
        outStage[row*4 + off]   = a0;
        outStage[row*4 + off+1] = a1;
    }
}

// ---- phase bodies (batch-parameterized) ----
__device__ __forceinline__ void ph0x(int st, const u16* Sb, u16* Ab, u16* Bb,
    u16* Db, u16* Eb, const float* biasT, int lane, int wid, int c0e,
    const bf16x8 (&WF1)[4], const bf16x8 (&WG1)[4],
    const bf16x8 (&WD1)[4], const bf16x8 (&WS1)[4])
{
    const bool doL1 = (st < TSTEPS), doDS = (st >= 1);
    float bF[4], bG[4], bD[4], bS[4];
    if (doL1) {
        float tt = st * DT_C;
        float sn = __sinf(tt), cn = __cosf(tt);
        float4 a0 = *(const float4*)(biasT + 0*128 + c0e);
        float4 a1 = *(const float4*)(biasT + 1*128 + c0e);
        float4 a2 = *(const float4*)(biasT + 2*128 + c0e);
        float4 a3 = *(const float4*)(biasT + 3*128 + c0e);
        float4 a4 = *(const float4*)(biasT + 4*128 + c0e);
        float4 a5 = *(const float4*)(biasT + 5*128 + c0e);
#pragma unroll
        for (int q = 0; q < 4; ++q) {
            bF[q] = ((const float*)&a0)[q] + sn*((const float*)&a1)[q] + cn*((const float*)&a2)[q];
            bG[q] = ((const float*)&a3)[q] + sn*((const float*)&a4)[q] + cn*((const float*)&a5)[q];
        }
    }
    if (doDS) {
        float4 a9 = *(const float4*)(biasT + 9*128 + c0e);
        float4 aa = *(const float4*)(biasT + 10*128 + c0e);
#pragma unroll
        for (int q = 0; q < 4; ++q) { bD[q]=((const float*)&a9)[q]; bS[q]=((const float*)&aa)[q]; }
    }
    if (doL1 && doDS) {
        f32x4 aF[2], aG[2], aD[2], aS[2];
        gemm4(Sb, WF1, WG1, WD1, WS1, lane, aF, aG, aD, aS);
        epiT(aF, bF, Ab, lane, wid);
        epiT(aG, bG, Bb, lane, wid);
        epiN(aD, bD, Db, lane, wid);
        epiN(aS, bS, Eb, lane, wid);
    } else if (doL1) {
        f32x4 aF[2], aG[2];
        gemm2(Sb, WF1, WG1, lane, aF, aG);
        epiT(aF, bF, Ab, lane, wid);
        epiT(aG, bG, Bb, lane, wid);
    } else if (doDS) {
        f32x4 aD[2], aS[2];
        gemm2(Sb, WD1, WS1, lane, aD, aS);
        epiN(aD, bD, Db, lane, wid);
        epiN(aS, bS, Eb, lane, wid);
    }
}

__device__ __forceinline__ void ph1x(int st, const u16* Ab, const u16* Bb, u16* Cb,
    const u16* Db, const u16* Eb, float* gpw, float* outS,
    const float4* ppd, const float4* pps, const float* biasT,
    int tid, int lane, int wid, int c0e,
    float db20, float db21, float sb20, float sb21,
    const bf16x8 (&WF2)[4], const bf16x8 (&WG2)[4])
{
    if (st < TSTEPS) {
        float4 b6 = *(const float4*)(biasT + 6*128 + c0e);
        float bb[4] = { b6.x, b6.y, b6.z, b6.w };
        f32x4 a1[2];
        gemm1(Ab, WF2, lane, a1);
        epiT(a1, bb, Cb, lane, wid);
        float4 b7 = *(const float4*)(biasT + 7*128 + c0e);
        float4 g3 = *(const float4*)(biasT + 11*128 + c0e);
        gemm1(Bb, WG2, lane, a1);
        float p0 = tanh_f(a1[0][0]+b7.x)*g3.x + tanh_f(a1[0][1]+b7.y)*g3.y
                 + tanh_f(a1[0][2]+b7.z)*g3.z + tanh_f(a1[0][3]+b7.w)*g3.w;
        float p1 = tanh_f(a1[1][0]+b7.x)*g3.x + tanh_f(a1[1][1]+b7.y)*g3.y
                 + tanh_f(a1[1][2]+b7.z)*g3.z + tanh_f(a1[1][3]+b7.w)*g3.w;
        p0 += __shfl_xor(p0, 16); p0 += __shfl_xor(p0, 32);
        p1 += __shfl_xor(p1, 16); p1 += __shfl_xor(p1, 32);
        if ((lane >> 4) == 0) {
            int rl2 = lane & 15;
            gpw[rl2*9 + wid]      = p0;
            gpw[(16+rl2)*9 + wid] = p1;
        }
    }
    if (st >= 1) {
        if (tid < 256) head_ln(Db, ppd, db20, db21, 0, 0, tid, outS);
        else           head_ln(Eb, pps, sb20, sb21, 1, 2, tid-256, outS);
    }
}

__device__ __forceinline__ void ph2x(int st, const u16* Cb, u16* Db,
    const float* gpr, const float* biasT, const float* __restrict__ nbase,
    float* __restrict__ wsb, const float* outS,
    int tid, int lane, int wid, int c0e, float gb3v,
    float4& nz0, float4& nz1, float& grow, const bf16x8 (&WF3)[4])
{
    if (st < TSTEPS) {
        const float* np = nbase + (size_t)st*NROWS*HD + (size_t)tid*8;
        nz0 = reinterpret_cast<const float4*>(np)[0];
        nz1 = reinterpret_cast<const float4*>(np)[1];
        float4 b8 = *(const float4*)(biasT + 8*128 + c0e);
        float bb[4] = { b8.x, b8.y, b8.z, b8.w };
        f32x4 a1[2];
        gemm1(Cb, WF3, lane, a1);
        epiN(a1, bb, Db, lane, wid);
        int row = tid >> 4, sub = tid & 15;
        float s = (sub < 8) ? gpr[row*9 + sub] : 0.f;
        s += __shfl_xor(s,1); s += __shfl_xor(s,2);
        s += __shfl_xor(s,4); s += __shfl_xor(s,8);
        grow = sigm_f(s + gb3v) * SQDT_C;
    }
    if (st >= 1 && tid < 128)
        wsb[(size_t)(st-1)*128 + tid] = outS[tid];
}

__device__ __forceinline__ void ph3x(int st, const u16* Db, u16* Sb, int tid,
    float (&y)[8], const float4& nz0, const float4& nz1, float grow)
{
    if (st >= TSTEPS) return;
    int row = tid >> 4, k0 = (tid & 15)*8, sk = SWZ(row, k0);
    uint4 dpk = *reinterpret_cast<const uint4*>(Db + row*HD + sk);
    y[0] += bf2f(dpk.x)     * DT_C + grow*nz0.x;
    y[1] += bf2f(dpk.x>>16) * DT_C + grow*nz0.y;
    y[2] += bf2f(dpk.y)     * DT_C + grow*nz0.z;
    y[3] += bf2f(dpk.y>>16) * DT_C + grow*nz0.w;
    y[4] += bf2f(dpk.z)     * DT_C + grow*nz1.x;
    y[5] += bf2f(dpk.z>>16) * DT_C + grow*nz1.y;
    y[6] += bf2f(dpk.w)     * DT_C + grow*nz1.z;
    y[7] += bf2f(dpk.w>>16) * DT_C + grow*nz1.w;
    uint4 s4 = { pack2(y[0],y[1]), pack2(y[2],y[3]), pack2(y[4],y[5]), pack2(y[6],y[7]) };
    *reinterpret_cast<uint4*>(Sb + row*HD + sk) = s4;
}

// ---- per-batch prologue (32 rows): pi head + mask + aggr -> y regs + Sb ----
__device__ __forceinline__ void prologueB(int rb0, u16* Xc, float* preLN, u16* Sb,
    const float* lE, const float* gE,
    const float* aggr_b, const float* aggr_g, const float* aggr_be,
    const float* pb1, const float* pg, const float* pbe,
    const float* pw2, const float* pb2,
    const unsigned char* pmask, const u16* wimg, float* outp,
    int tid, int lane, int wid, float (&y)[8])
{
#pragma unroll
    for (int i = 0; i < 2; ++i) {
        int gidx = i*512 + tid;
        int r = gidx >> 5;
        int k = (gidx & 31) * 8;
        int gr = rb0 + r;
        const float* src = (k < HD) ? (gE + (size_t)gr*HD + k)
                                    : (lE + (size_t)(gr & (Adim-1))*HD + (k - HD));
        float4 v0 = reinterpret_cast<const float4*>(src)[0];
        float4 v1 = reinterpret_cast<const float4*>(src)[1];
        uint4 pk = { pack2(v0.x, v0.y), pack2(v0.z, v0.w),
                     pack2(v1.x, v1.y), pack2(v1.z, v1.w) };
        *reinterpret_cast<uint4*>(Xc + r*256 + SWZ(r, k)) = pk;
    }
    __syncthreads();
    f32x4 acc[2];
    gemmX(Xc, 0,   wimg + 10*16384, lane, wid, acc, true);
    gemmX(Xc, 128, wimg + 9*16384,  lane, wid, acc, false);
    epiF(acc, pb1, preLN, lane, wid);
    __syncthreads();
    {
        int row = tid >> 4, sub = tid & 15;
        int c0 = sub * 8;
        const float* yr = preLN + row*HD + c0;
        float v[8]; float s = 0.f, sq = 0.f;
#pragma unroll
        for (int i = 0; i < 8; ++i){ float x = yr[i]; v[i] = x; s += x; sq += x*x; }
        s += __shfl_xor(s,1); sq += __shfl_xor(sq,1);
        s += __shfl_xor(s,2); sq += __shfl_xor(sq,2);
        s += __shfl_xor(s,4); sq += __shfl_xor(sq,4);
        s += __shfl_xor(s,8); sq += __shfl_xor(sq,8);
        float mu = s*(1.f/128.f);
        float rstd = rsqrtf(sq*(1.f/128.f) - mu*mu + LN_EPS);
        float a0 = 0.f;
#pragma unroll
        for (int i = 0; i < 8; ++i){
            int cc = c0 + i;
            float h = (v[i]-mu)*rstd*pg[cc] + pbe[cc];
            a0 += fmaxf(h, 0.f) * pw2[cc];
        }
        a0 += __shfl_xor(a0,1); a0 += __shfl_xor(a0,2);
        a0 += __shfl_xor(a0,4); a0 += __shfl_xor(a0,8);
        if (sub == 0) {
            int gr = rb0 + row;
            outp[PI_OFF + (size_t)(gr & (Adim-1))*6 + (gr >> 12)] = a0 + pb2[0];
        }
    }
    if (tid < 32) {
        int gr = rb0 + tid;
        if (gr < Adim) {
            const unsigned char* pm = pmask + (size_t)gr*50 + 20;
            float* o = outp + MASK_OFF + (size_t)gr*TSTEPS;
#pragma unroll
            for (int i = 0; i < TSTEPS; ++i) o[i] = pm[i] ? 0.f : 1.f;
        }
    }
    __syncthreads();
    gemmX(Xc, 0,   wimg + 7*16384, lane, wid, acc, true);
    gemmX(Xc, 128, wimg + 8*16384, lane, wid, acc, false);
    epiF(acc, aggr_b, preLN, lane, wid);
    __syncthreads();
    {
        int row = tid >> 4, sub = tid & 15;
        int c0 = sub * 8;
        const float* yr = preLN + row*HD + c0;
        float v[8]; float s = 0.f, sq = 0.f;
#pragma unroll
        for (int i = 0; i < 8; ++i){ float x = yr[i]; v[i] = x; s += x; sq += x*x; }
        s += __shfl_xor(s,1); sq += __shfl_xor(sq,1);
        s += __shfl_xor(s,2); sq += __shfl_xor(sq,2);
        s += __shfl_xor(s,4); sq += __shfl_xor(sq,4);
        s += __shfl_xor(s,8); sq += __shfl_xor(sq,8);
        float mu = s*(1.f/128.f);
        float rstd = rsqrtf(sq*(1.f/128.f) - mu*mu + LN_EPS);
#pragma unroll
        for (int i = 0; i < 8; ++i){
            int cc = c0 + i;
            float h = (v[i]-mu)*rstd*aggr_g[cc] + aggr_be[cc];
            v[i] = fmaxf(h, 0.f);
        }
#pragma unroll
        for (int i = 0; i < 8; ++i) y[i] = v[i];
        uint4 pk = { pack2(v[0],v[1]), pack2(v[2],v[3]),
                     pack2(v[4],v[5]), pack2(v[6],v[7]) };
        *reinterpret_cast<uint4*>(&Sb[row*HD + SWZ(row, c0)]) = pk;
    }
    __syncthreads();
}

// ---------- weight image prep: f32 -> bf16, transposed, swizzled ----------
__global__ void prep_w(const float* __restrict__ fw1, const float* __restrict__ fw2,
                       const float* __restrict__ fw3, const float* __restrict__ gw1,
                       const float* __restrict__ gw2, const float* __restrict__ dw1,
                       const float* __restrict__ sw1, const float* __restrict__ aw,
                       const float* __restrict__ pw1, u16* __restrict__ ws)
{
    int img = blockIdx.y;
    int idx = blockIdx.x * 256 + threadIdx.x;
    int k = idx >> 7, j = idx & 127;
    const float* W = fw1; int sr = k;
    switch (img) {
        case 0: W = fw1; break;  case 1: W = fw2; break;  case 2: W = fw3; break;
        case 3: W = gw1; break;  case 4: W = gw2; break;
        case 5: W = dw1; break;  case 6: W = sw1; break;
        case 7: W = aw;  break;  case 8: W = aw;  sr = k + 128; break;
        case 9: W = pw1; break;  case 10: W = pw1; sr = k + 128; break;
    }
    ws[(size_t)img*16384 + j*128 + SWZ(j, k)] = f2bf(W[(size_t)sr*128 + j]);
}

// ---------- final output reorder: ws [vb][tt][row][4] -> loc_out [gr][tt][4] ----------
__global__ void reorder_out(const float* __restrict__ wsOut, float* __restrict__ outp)
{
    __shared__ float tile[3840];
    int b = blockIdx.x;
    const float* src = wsOut + (size_t)b*3840;
#pragma unroll
    for (int j = 0; j < 15; ++j) {
        int idx = j*256 + threadIdx.x;
        int tt = idx >> 7, rc = idx & 127;
        int row = rc >> 2, c = idx & 3;
        tile[row*120 + tt*4 + c] = src[idx];
    }
    __syncthreads();
    float* dst = outp + (size_t)b*3840;
#pragma unroll
    for (int j = 0; j < 15; ++j) {
        int idx = j*256 + threadIdx.x;
        dst[idx] = tile[idx];
    }
}

// ---------- the fused persistent kernel: 3-batch software pipeline ----------
__global__ __launch_bounds__(512, 2) void sde_fused(
    const float* __restrict__ lE, const float* __restrict__ gE,
    const float* __restrict__ noise,
    const float* __restrict__ aggr_b, const float* __restrict__ aggr_g, const float* __restrict__ aggr_be,
    const float* __restrict__ fw1, const float* __restrict__ fb1,
    const float* __restrict__ fb2, const float* __restrict__ fb3,
    const float* __restrict__ gw1, const float* __restrict__ gb1,
    const float* __restrict__ gb2, const float* __restrict__ gw3, const float* __restrict__ gb3,
    const float* __restrict__ db1, const float* __restrict__ dg, const float* __restrict__ dbe,
    const float* __restrict__ dw2, const float* __restrict__ db2,
    const float* __restrict__ sb1, const float* __restrict__ sg, const float* __restrict__ sbe,
    const float* __restrict__ sw2, const float* __restrict__ sb2,
    const float* __restrict__ pb1, const float* __restrict__ pg, const float* __restrict__ pbe,
    const float* __restrict__ pw2, const float* __restrict__ pb2,
    const unsigned char* __restrict__ pmask,
    const u16* __restrict__ wimg,
    float* __restrict__ wsOut,
    float* __restrict__ outp)
{
    // LDS: 3 batches x {Sb,Ab,Bb,Cb,Db,Eb} (6 x 8KB = 48KB each) = 147456
    //      gpart[2][32][9] f32 @147456 (2304) | biasT[12][128] @149760 (6144)
    //      ppd @155904 (2048) | pps @157952 (2048) | outStage 3x128 @160000 (1536)
    __shared__ __align__(16) unsigned char SMEM[161536];
    u16* Sb0 = (u16*)(SMEM +      0); u16* Ab0 = (u16*)(SMEM +  8192);
    u16* Bb0 = (u16*)(SMEM +  16384); u16* Cb0 = (u16*)(SMEM + 24576);
    u16* Db0 = (u16*)(SMEM +  32768); u16* Eb0 = (u16*)(SMEM + 40960);
    u16* Sb1 = (u16*)(SMEM +  49152); u16* Ab1 = (u16*)(SMEM + 57344);
    u16* Bb1 = (u16*)(SMEM +  65536); u16* Cb1 = (u16*)(SMEM + 73728);
    u16* Db1 = (u16*)(SMEM +  81920); u16* Eb1 = (u16*)(SMEM + 90112);
    u16* Sb2 = (u16*)(SMEM +  98304); u16* Ab2 = (u16*)(SMEM + 106496);
    u16* Bb2 = (u16*)(SMEM + 114688); u16* Cb2 = (u16*)(SMEM + 122880);
    u16* Db2 = (u16*)(SMEM + 131072); u16* Eb2 = (u16*)(SMEM + 139264);
    float* gpart = (float*)(SMEM + 147456);      // [2][288]
    float* biasT = (float*)(SMEM + 149760);      // [12][128]
    float4* ppd  = (float4*)(SMEM + 155904);
    float4* pps  = (float4*)(SMEM + 157952);
    float* outS0 = (float*)(SMEM + 160000);
    float* outS1 = (float*)(SMEM + 160512);
    float* outS2 = (float*)(SMEM + 161024);

    const int tid  = threadIdx.x;
    const int lane = tid & 63;
    const int wid  = tid >> 6;
    const int bid  = blockIdx.x;
    const int r0   = bid * RBLK;
    const int c0e  = wid*16 + ((lane>>4)<<2);

    // stage params
    if (tid < 128) {
        int cs = tid ^ ((tid >> 4) & 7);
        ppd[cs] = make_float4(dg[tid], dbe[tid], dw2[2*tid], dw2[2*tid+1]);
        pps[cs] = make_float4(sg[tid], sbe[tid], sw2[2*tid], sw2[2*tid+1]);
        biasT[0*128+tid]  = fb1[tid];
        biasT[1*128+tid]  = fw1[128*HD+tid];
        biasT[2*128+tid]  = fw1[129*HD+tid];
        biasT[3*128+tid]  = gb1[tid];
        biasT[4*128+tid]  = gw1[128*HD+tid];
        biasT[5*128+tid]  = gw1[129*HD+tid];
        biasT[6*128+tid]  = fb2[tid];
        biasT[7*128+tid]  = gb2[tid];
        biasT[8*128+tid]  = fb3[tid];
        biasT[9*128+tid]  = db1[tid];
        biasT[10*128+tid] = sb1[tid];
        biasT[11*128+tid] = gw3[tid];
    }

    float y0[8], y1[8], y2[8];
    // prologues (Xc aliases Ab..Bb, preLN aliases Cb..Db of each batch)
    prologueB(r0,    Ab0, (float*)Cb0, Sb0, lE, gE, aggr_b, aggr_g, aggr_be,
              pb1, pg, pbe, pw2, pb2, pmask, wimg, outp, tid, lane, wid, y0);
    prologueB(r0+32, Ab1, (float*)Cb1, Sb1, lE, gE, aggr_b, aggr_g, aggr_be,
              pb1, pg, pbe, pw2, pb2, pmask, wimg, outp, tid, lane, wid, y1);
    prologueB(r0+64, Ab2, (float*)Cb2, Sb2, lE, gE, aggr_b, aggr_g, aggr_be,
              pb1, pg, pbe, pw2, pb2, pmask, wimg, outp, tid, lane, wid, y2);

    // loop weights into registers (112 VGPR)
    bf16x8 WF1[4], WG1[4], WF2[4], WG2[4], WF3[4], WD1[4], WS1[4];
    loadW(wimg + 0*16384, lane, wid, WF1);
    loadW(wimg + 3*16384, lane, wid, WG1);
    loadW(wimg + 1*16384, lane, wid, WF2);
    loadW(wimg + 4*16384, lane, wid, WG2);
    loadW(wimg + 2*16384, lane, wid, WF3);
    loadW(wimg + 5*16384, lane, wid, WD1);
    loadW(wimg + 6*16384, lane, wid, WS1);

    const float db20 = db2[0], db21 = db2[1];
    const float sb20 = sb2[0], sb21 = sb2[1];
    const float gb3v = gb3[0];

    const float* nb0 = noise + (size_t)(r0     )*HD;
    const float* nb1 = noise + (size_t)(r0 + 32)*HD;
    const float* nb2 = noise + (size_t)(r0 + 64)*HD;
    float* ws0 = wsOut + (size_t)(bid*3 + 0)*TSTEPS*128;
    float* ws1 = wsOut + (size_t)(bid*3 + 1)*TSTEPS*128;
    float* ws2 = wsOut + (size_t)(bid*3 + 2)*TSTEPS*128;

    float4 nA0, nA1, nB0, nB1, nC0, nC1;
    float gA = 0.f, gB = 0.f, gC = 0.f;

    __syncthreads();

    const int TMAX = 4*TSTEPS + 2;
    for (int iv = 0; iv <= 4*TSTEPS + 4; ++iv) {
        const int par = iv & 1, rpar = par ^ 1;
        { // batch 0
            int t = iv;
            if (t <= TMAX) {
                int ph = t & 3, st = t >> 2;
                if      (ph == 0) ph0x(st, Sb0, Ab0, Bb0, Db0, Eb0, biasT, lane, wid, c0e, WF1, WG1, WD1, WS1);
                else if (ph == 1) ph1x(st, Ab0, Bb0, Cb0, Db0, Eb0, gpart + par*288, outS0,
                                       ppd, pps, biasT, tid, lane, wid, c0e, db20, db21, sb20, sb21, WF2, WG2);
                else if (ph == 2) ph2x(st, Cb0, Db0, gpart + rpar*288, biasT, nb0, ws0, outS0,
                                       tid, lane, wid, c0e, gb3v, nA0, nA1, gA, WF3);
                else              ph3x(st, Db0, Sb0, tid, y0, nA0, nA1, gA);
            }
        }
        { // batch 1
            int t = iv - 1;
            if (t >= 0 && t <= TMAX) {
                int ph = t & 3, st = t >> 2;
                if      (ph == 0) ph0x(st, Sb1, Ab1, Bb1, Db1, Eb1, biasT, lane, wid, c0e, WF1, WG1, WD1, WS1);
                else if (ph == 1) ph1x(st, Ab1, Bb1, Cb1, Db1, Eb1, gpart + par*288, outS1,
                                       ppd, pps, biasT, tid, lane, wid, c0e, db20, db21, sb20, sb21, WF2, WG2);
                else if (ph == 2) ph2x(st, Cb1, Db1, gpart + rpar*288, biasT, nb1, ws1, outS1,
                                       tid, lane, wid, c0e, gb3v, nB0, nB1, gB, WF3);
                else              ph3x(st, Db1, Sb1, tid, y1, nB0, nB1, gB);
            }
        }
        { // batch 2
            int t = iv - 2;
            if (t >= 0 && t <= TMAX) {
                int ph = t & 3, st = t >> 2;
                if      (ph == 0) ph0x(st, Sb2, Ab2, Bb2, Db2, Eb2, biasT, lane, wid, c0e, WF1, WG1, WD1, WS1);
                else if (ph == 1) ph1x(st, Ab2, Bb2, Cb2, Db2, Eb2, gpart + par*288, outS2,
                                       ppd, pps, biasT, tid, lane, wid, c0e, db20, db21, sb20, sb21, WF2, WG2);
                else if (ph == 2) ph2x(st, Cb2, Db2, gpart + rpar*288, biasT, nb2, ws2, outS2,
                                       tid, lane, wid, c0e, gb3v, nC0, nC1, gC, WF3);
                else              ph3x(st, Db2, Sb2, tid, y2, nC0, nC1, gC);
            }
        }
        __syncthreads();
    }
}

extern "C" void kernel_launch(void* const* d_in, const int* in_sizes, int n_in,
                              void* d_out, int out_size, void* d_ws, size_t ws_size,
                              hipStream_t stream) {
    const float* lE      = (const float*)d_in[0];
    const float* gE      = (const float*)d_in[1];
    const float* noise   = (const float*)d_in[2];
    const float* aggr_w  = (const float*)d_in[3];
    const float* aggr_b  = (const float*)d_in[4];
    const float* aggr_g  = (const float*)d_in[5];
    const float* aggr_be = (const float*)d_in[6];
    const float* fw1 = (const float*)d_in[7];
    const float* fb1 = (const float*)d_in[8];
    const float* fw2 = (const float*)d_in[9];
    const float* fb2 = (const float*)d_in[10];
    const float* fw3 = (const float*)d_in[11];
    const float* fb3 = (const float*)d_in[12];
    const float* gw1 = (const float*)d_in[13];
    const float* gb1 = (const float*)d_in[14];
    const float* gw2 = (const float*)d_in[15];
    const float* gb2 = (const float*)d_in[16];
    const float* gw3 = (const float*)d_in[17];
    const float* gb3 = (const float*)d_in[18];
    const float* dw1 = (const float*)d_in[19];
    const float* db1 = (const float*)d_in[20];
    const float* dg  = (const float*)d_in[21];
    const float* dbe = (const float*)d_in[22];
    const float* dw2 = (const float*)d_in[23];
    const float* db2 = (const float*)d_in[24];
    const float* sw1 = (const float*)d_in[25];
    const float* sb1 = (const float*)d_in[26];
    const float* sg  = (const float*)d_in[27];
    const float* sbe = (const float*)d_in[28];
    const float* sw2 = (const float*)d_in[29];
    const float* sb2 = (const float*)d_in[30];
    const float* pw1 = (const float*)d_in[31];
    const float* pb1 = (const float*)d_in[32];
    const float* pg  = (const float*)d_in[33];
    const float* pbe = (const float*)d_in[34];
    const float* pw2 = (const float*)d_in[35];
    const float* pb2 = (const float*)d_in[36];
    const unsigned char* pmask = (const unsigned char*)d_in[37];
    float* outp = (float*)d_out;
    u16* wimg = (u16*)d_ws;                                  // 352 KB
    float* wsOut = (float*)((char*)d_ws + 360448);           // 768*3840 floats = 11.8 MB

    prep_w<<<dim3(64, 11), 256, 0, stream>>>(fw1, fw2, fw3, gw1, gw2, dw1, sw1,
                                             aggr_w, pw1, wimg);
    sde_fused<<<NBLKS, 512, 0, stream>>>(
        lE, gE, noise, aggr_b, aggr_g, aggr_be,
        fw1, fb1, fb2, fb3,
        gw1, gb1, gb2, gw3, gb3,
        db1, dg, dbe, dw2, db2,
        sb1, sg, sbe, sw2, sb2,
        pb1, pg, pbe, pw2, pb2,
        pmask, wimg, wsOut, outp);
    reorder_out<<<768, 256, 0, stream>>>(wsOut, outp);
}